// Round 8
// baseline (94.084 us; speedup 1.0000x reference)
//
#include <hip/hip_runtime.h>
#include <hip/hip_bf16.h>

#define SROWS 16384
#define DIMK  4096
#define NE    64
#define BM    32
#define NBLK  (SROWS/BM)        // 512 blocks = 2/CU
#define BK    64                // k per staged chunk
#define NCHK  (DIMK/BK)         // 64 chunks
#define WSPLIT_SHORTS 262144    // shorts per (hi|lo) plane of pre-split W
#define WSOFF_F 262144          // f32 offset of partials region (skip 1 MB W-split)
#define WSOFF2  (WSOFF_F + NBLK*64)
#define LDS_BYTES 73728         // 3 x (8 KB x + 16 KB B)

typedef __attribute__((ext_vector_type(8))) short short8;
typedef __attribute__((ext_vector_type(4))) float f32x4;

// split 8 f32 -> 8 hi bf16 + 8 lo bf16 via HW cvt (RNE); f ~= hi + lo
__device__ __forceinline__ void split8(const float4 a, const float4 c, short8& hi, short8& lo) {
    float f[8] = {a.x, a.y, a.z, a.w, c.x, c.y, c.z, c.w};
    #pragma unroll
    for (int i = 0; i < 8; ++i) {
        unsigned short h = __bfloat16_as_ushort(__float2bfloat16(f[i]));
        float hf = __uint_as_float((unsigned)h << 16);
        unsigned short l = __bfloat16_as_ushort(__float2bfloat16(f[i] - hf));
        hi[i] = (short)h;
        lo[i] = (short)l;
    }
}

// pre-pass: split W into bf16 hi/lo planes in B-fragment order [k/8][e][8]
__global__ void w_split(const float* __restrict__ W, unsigned short* __restrict__ wsp)
{
    const int idx   = blockIdx.x * 256 + threadIdx.x;   // 0..32767
    const int kslot = idx & 511;
    const int e     = idx >> 9;
    const float* p = W + (size_t)e * DIMK + kslot * 8;
    float4 va = *reinterpret_cast<const float4*>(p);
    float4 vb = *reinterpret_cast<const float4*>(p + 4);
    short8 hi, lo;
    split8(va, vb, hi, lo);
    *reinterpret_cast<short8*>(wsp + (size_t)(kslot * 64 + e) * 8)                 = hi;
    *reinterpret_cast<short8*>(wsp + WSPLIT_SHORTS + (size_t)(kslot * 64 + e) * 8) = lo;
}

// async global -> LDS, 16B per lane (DMA; no dest VGPRs)
__device__ __forceinline__ void gl_lds16(const void* g, void* l) {
    __builtin_amdgcn_global_load_lds(
        (const __attribute__((address_space(1))) void*)g,
        (__attribute__((address_space(3))) void*)l, 16, 0, 0);
}

__global__ __launch_bounds__(256, 2) void gate_main(
    const float* __restrict__ x, const unsigned short* __restrict__ wsp,
    const float* __restrict__ b, float* __restrict__ out, float* __restrict__ ws)
{
    extern __shared__ __align__(16) char smem[];
    // buffer i (i=0..2): x at smem + i*8192 (8 KB, [32 rows][64 k] f32, src-swizzled)
    //                    B at smem + 24576 + i*16384 (hi 8 KB | lo 8 KB, frag order)

    const int tid  = threadIdx.x;
    const int lane = tid & 63;
    const int wid  = __builtin_amdgcn_readfirstlane(tid >> 6);  // 0..3
    const int mw   = wid & 1;      // M-tile (16 rows)
    const int ksw  = wid >> 1;     // K32 half of the BK=64 chunk
    const int row0 = blockIdx.x * BM;

    // ---- staging addresses ----
    const int s0 = tid, s1 = 256 + tid;
    const int r0 = s0 >> 4, k0 = (s0 & 15) ^ (r0 & 7);
    const int r1 = s1 >> 4, k1 = (s1 & 15) ^ (r1 & 7);
    const float* xsrc0 = x + (size_t)(row0 + r0) * DIMK + k0 * 4;
    const float* xsrc1 = x + (size_t)(row0 + r1) * DIMK + k1 * 4;
    const unsigned short* bsrcH = wsp + (size_t)tid * 8;
    const unsigned short* bsrcL = bsrcH + WSPLIT_SHORTS;

    auto STAGE = [&](int ch, int bsel) {
        char* xb = smem + bsel * 8192;
        char* Bb = smem + 24576 + bsel * 16384;
        gl_lds16(xsrc0 + (size_t)ch * BK, xb + s0 * 16);
        gl_lds16(xsrc1 + (size_t)ch * BK, xb + s1 * 16);
        const unsigned short* hp = bsrcH + (size_t)ch * 4096;
        const unsigned short* lp = bsrcL + (size_t)ch * 4096;
        gl_lds16(hp,        Bb + tid * 16);
        gl_lds16(hp + 2048, Bb + 4096 + tid * 16);
        gl_lds16(lp,        Bb + 8192 + tid * 16);
        gl_lds16(lp + 2048, Bb + 12288 + tid * 16);
    };

    f32x4 acc[4];
    #pragma unroll
    for (int n = 0; n < 4; ++n) acc[n] = (f32x4){0.f, 0.f, 0.f, 0.f};

    // fragment offsets (consume-side)
    const int row_l = mw * 16 + (lane & 15);
    const int abase = row_l * 256 + ksw * 128 + (lane >> 4) * 32;
    const int axor  = (row_l & 7) << 4;               // matches source pre-swizzle
    const int kl    = ksw * 4 + (lane >> 4);          // local kslot 0..7
    const int bfo   = (kl * 64 + (lane & 15)) * 16;   // byte offset in B plane

    // ---- prologue: 2 chunks in flight ----
    STAGE(0, 0);
    STAGE(1, 1);

    #pragma unroll 1
    for (int ch = 0; ch < NCHK; ++ch) {
        // counted wait: chunk ch's 6 loads done; chunk ch+1's 6 stay in flight
        if (ch + 1 < NCHK) asm volatile("s_waitcnt vmcnt(6)" ::: "memory");
        else               asm volatile("s_waitcnt vmcnt(0)" ::: "memory");
        __builtin_amdgcn_s_barrier();
        __builtin_amdgcn_sched_barrier(0);

        // refill the buffer freed one iteration ago (depth-2 prefetch)
        if (ch + 2 < NCHK) STAGE(ch + 2, (ch + 2) % 3);

        const int cur = ch % 3;
        const char* xb = smem + cur * 8192;
        const char* Bb = smem + 24576 + cur * 16384;

        float4 xa = *reinterpret_cast<const float4*>(xb + ((abase) ^ axor));
        float4 xc = *reinterpret_cast<const float4*>(xb + ((abase + 16) ^ axor));
        short8 ah, al;
        split8(xa, xc, ah, al);

        short8 bh[4], bl[4];
        #pragma unroll
        for (int n = 0; n < 4; ++n) {
            bh[n] = *reinterpret_cast<const short8*>(Bb + bfo + n * 256);
            bl[n] = *reinterpret_cast<const short8*>(Bb + 8192 + bfo + n * 256);
        }

        #pragma unroll
        for (int n = 0; n < 4; ++n)
            acc[n] = __builtin_amdgcn_mfma_f32_16x16x32_bf16(ah, bh[n], acc[n], 0, 0, 0);
        #pragma unroll
        for (int n = 0; n < 4; ++n)
            acc[n] = __builtin_amdgcn_mfma_f32_16x16x32_bf16(ah, bl[n], acc[n], 0, 0, 0);
        #pragma unroll
        for (int n = 0; n < 4; ++n)
            acc[n] = __builtin_amdgcn_mfma_f32_16x16x32_bf16(al, bh[n], acc[n], 0, 0, 0);
    }

    __syncthreads();   // one-time full drain before LDS reuse

    // ---- epilogue: reuse smem ----
    float* const part = reinterpret_cast<float*>(smem);            // 2048 f32
    float* const Lb   = reinterpret_cast<float*>(smem + 8192);     // [64 e][33]
    float* const red  = reinterpret_cast<float*>(smem + 17408);    // 512 f32

    if (ksw == 1) {
        #pragma unroll
        for (int n = 0; n < 4; ++n)
            #pragma unroll
            for (int j = 0; j < 4; ++j)
                part[mw * 1024 + lane * 16 + n * 4 + j] = acc[n][j];
    }
    __syncthreads();
    if (ksw == 0) {
        #pragma unroll
        for (int n = 0; n < 4; ++n) {
            #pragma unroll
            for (int j = 0; j < 4; ++j) {
                float v = acc[n][j] + part[mw * 1024 + lane * 16 + n * 4 + j];
                // C layout (m89-verified): col = lane&15, row = (lane>>4)*4 + j
                const int e  = n * 16 + (lane & 15);
                const int rl = mw * 16 + (lane >> 4) * 4 + j;
                Lb[e * 33 + rl] = v;
            }
        }
    }
    __syncthreads();

    // ---- softmax + top-2 per row (lane = expert), 8 rows/wave ----
    float impAcc = 0.f, cntAcc = 0.f;
    const float blane = b[lane];
    float* outIdx = out;
    float* outVal = out + (size_t)SROWS * 2;

    #pragma unroll 1
    for (int rr = 0; rr < 8; ++rr) {
        const int r = wid * 8 + rr;
        const float logit = Lb[lane * 33 + r] + blane;

        float v1 = logit; int i1 = lane;
        #pragma unroll
        for (int off = 32; off; off >>= 1) {
            float ov = __shfl_xor(v1, off);
            int   oi = __shfl_xor(i1, off);
            if (ov > v1 || (ov == v1 && oi < i1)) { v1 = ov; i1 = oi; }
        }
        float p = expf(logit - v1);
        float ssum = p;
        #pragma unroll
        for (int off = 32; off; off >>= 1) ssum += __shfl_xor(ssum, off);

        float v2 = (lane == i1) ? -3.402823466e38f : logit;
        int i2 = lane;
        #pragma unroll
        for (int off = 32; off; off >>= 1) {
            float ov = __shfl_xor(v2, off);
            int   oi = __shfl_xor(i2, off);
            if (ov > v2 || (ov == v2 && oi < i2)) { v2 = ov; i2 = oi; }
        }

        impAcc += p / ssum;
        cntAcc += (i1 == lane) ? 1.f : 0.f;

        if (lane == 0) {
            const int sr = row0 + r;
            outIdx[sr * 2 + 0] = (float)i1;
            outIdx[sr * 2 + 1] = (float)i2;
            outVal[sr * 2 + 0] = 1.f / ssum;
            outVal[sr * 2 + 1] = expf(v2 - v1) / ssum;
        }
    }

    // ---- per-block reduce of importance / count partials ----
    __syncthreads();
    red[wid * 64 + lane]       = impAcc;
    red[256 + wid * 64 + lane] = cntAcc;
    __syncthreads();
    if (tid < 64) {
        float si = 0.f, sc2 = 0.f;
        #pragma unroll
        for (int g = 0; g < 4; ++g) {
            si  += red[g * 64 + tid];
            sc2 += red[256 + g * 64 + tid];
        }
        ws[WSOFF_F + (size_t)blockIdx.x * 64 + tid] = si;
        ws[WSOFF2  + (size_t)blockIdx.x * 64 + tid] = sc2;
    }
}

__global__ void gate_reduce(const float* __restrict__ ws, float* __restrict__ out)
{
    __shared__ float li[8 * 64], lc[8 * 64], lp[64];
    const int t = threadIdx.x;
    const int e = t & 63, g = t >> 6;      // 8 groups x 64 blocks each
    float si = 0.f, sc = 0.f;
    const int base = g * 64;
    #pragma unroll 4
    for (int bb = base; bb < base + 64; ++bb) {
        si += ws[WSOFF_F + (size_t)bb * 64 + e];
        sc += ws[WSOFF2  + (size_t)bb * 64 + e];
    }
    li[g * 64 + e] = si;
    lc[g * 64 + e] = sc;
    __syncthreads();
    if (t < 64) {
        float ti = 0.f, tc = 0.f;
        #pragma unroll
        for (int gg = 0; gg < 8; ++gg) { ti += li[gg * 64 + t]; tc += lc[gg * 64 + t]; }
        lp[t] = ti * tc;
    }
    __syncthreads();
    if (t == 0) {
        float s = 0.f;
        for (int i = 0; i < NE; ++i) s += lp[i];
        out[(size_t)SROWS * 4] = s * ((float)NE / ((float)SROWS * (float)SROWS));
    }
}

extern "C" void kernel_launch(void* const* d_in, const int* in_sizes, int n_in,
                              void* d_out, int out_size, void* d_ws, size_t ws_size,
                              hipStream_t stream)
{
    const float* x = (const float*)d_in[0];
    const float* W = (const float*)d_in[1];
    const float* b = (const float*)d_in[2];
    float* out = (float*)d_out;
    unsigned short* wsp = (unsigned short*)d_ws;
    float* wsf = (float*)d_ws;

    // allow 72 KB dynamic LDS (host-side attribute; not a stream op, capture-safe)
    static_assert(LDS_BYTES <= 160 * 1024 / 2, "2 blocks/CU LDS budget");
    hipFuncSetAttribute(reinterpret_cast<const void*>(gate_main),
                        hipFuncAttributeMaxDynamicSharedMemorySize, LDS_BYTES);

    w_split<<<128, 256, 0, stream>>>(W, wsp);
    gate_main<<<NBLK, 256, LDS_BYTES, stream>>>(x, wsp, b, out, wsf);
    gate_reduce<<<1, 512, 0, stream>>>(wsf, out);
}

// Round 9
// 81.487 us; speedup vs baseline: 1.1546x; 1.1546x over previous
//
#include <hip/hip_runtime.h>
#include <hip/hip_bf16.h>

#define SROWS 16384
#define DIMK  4096
#define NE    64
#define BM    16                // rows per block
#define NBLK  (SROWS/BM)        // 1024 blocks = 4/CU
#define KSEG  1024              // k-range per wave (4-way k-split)
#define NSTEP 16                // steps; per step each wave consumes 64 k
#define SBK   64
#define WSPLIT_SHORTS 262144    // shorts per (hi|lo) plane of pre-split W
#define WSOFF_F 262144          // f32 offset of partials region (skip 1 MB W-split)
#define WSOFF2  (WSOFF_F + NBLK*64)

typedef __attribute__((ext_vector_type(8))) short short8;
typedef __attribute__((ext_vector_type(4))) float f32x4;

// split 8 f32 -> 8 hi bf16 + 8 lo bf16 via HW cvt (RNE); f ~= hi + lo
__device__ __forceinline__ void split8(const float4 a, const float4 c, short8& hi, short8& lo) {
    float f[8] = {a.x, a.y, a.z, a.w, c.x, c.y, c.z, c.w};
    #pragma unroll
    for (int i = 0; i < 8; ++i) {
        unsigned short h = __bfloat16_as_ushort(__float2bfloat16(f[i]));
        float hf = __uint_as_float((unsigned)h << 16);
        unsigned short l = __bfloat16_as_ushort(__float2bfloat16(f[i] - hf));
        hi[i] = (short)h;
        lo[i] = (short)l;
    }
}

// pre-pass: split W into bf16 hi/lo planes in B-fragment order [k/8][e][8]
__global__ void w_split(const float* __restrict__ W, unsigned short* __restrict__ wsp)
{
    const int idx   = blockIdx.x * 256 + threadIdx.x;   // 0..32767
    const int kslot = idx & 511;
    const int e     = idx >> 9;
    const float* p = W + (size_t)e * DIMK + kslot * 8;
    float4 va = *reinterpret_cast<const float4*>(p);
    float4 vb = *reinterpret_cast<const float4*>(p + 4);
    short8 hi, lo;
    split8(va, vb, hi, lo);
    *reinterpret_cast<short8*>(wsp + (size_t)(kslot * 64 + e) * 8)                 = hi;
    *reinterpret_cast<short8*>(wsp + WSPLIT_SHORTS + (size_t)(kslot * 64 + e) * 8) = lo;
}

// async global -> LDS, 16B per lane (DMA; no dest VGPRs)
__device__ __forceinline__ void gl_lds16(const void* g, void* l) {
    __builtin_amdgcn_global_load_lds(
        (const __attribute__((address_space(1))) void*)g,
        (__attribute__((address_space(3))) void*)l, 16, 0, 0);
}

__global__ __launch_bounds__(256, 4) void gate_main(
    const float* __restrict__ x, const unsigned short* __restrict__ wsp,
    const float* __restrict__ b, float* __restrict__ out, float* __restrict__ ws)
{
    __shared__ __align__(16) char smem[32768];
    // main loop: 2 x-buffers of 16 KB, layout [ksw(4)][row(16)][16 granules x 16B], src-swizzled
    // epilogue alias: part[3072 f32] | Lb[64*17 f32] | red[512 f32]

    const int tid  = threadIdx.x;
    const int lane = tid & 63;
    const int ksw  = __builtin_amdgcn_readfirstlane(tid >> 6);  // 0..3 (k-split)
    const int row0 = blockIdx.x * BM;

    // ---- staging source pointers: 4 slots/thread, granule XOR-swizzled ----
    const float* xsq[4];
    int dsts[4];
    #pragma unroll
    for (int q = 0; q < 4; ++q) {
        const int s   = q * 256 + tid;     // 0..1023
        const int kss = s >> 8;            // section = k-split wave
        const int row = (s >> 4) & 15;
        const int gs  = (s & 15) ^ (row & 7);
        xsq[q]  = x + (size_t)(row0 + row) * DIMK + kss * KSEG + gs * 4;
        dsts[q] = s * 16;
    }

    auto STAGE = [&](int st, int bsel) {
        char* xb = smem + bsel * 16384;
        #pragma unroll
        for (int q = 0; q < 4; ++q)
            gl_lds16(xsq[q] + (size_t)st * SBK, xb + dsts[q]);
    };

    f32x4 acc[4];
    #pragma unroll
    for (int n = 0; n < 4; ++n) acc[n] = (f32x4){0.f, 0.f, 0.f, 0.f};

    const int rm = (lane & 7) & 7;                 // row&7 for consume swizzle (row = lane&15)
    const char* xsec_base = smem + ksw * 4096 + (lane & 15) * 256;
    const unsigned short* wBbase = wsp + ((size_t)(ksw * 128) * 64) * 8;

    STAGE(0, 0);

    #pragma unroll 1
    for (int st = 0; st < NSTEP; ++st) {
        asm volatile("s_waitcnt vmcnt(0)" ::: "memory");   // only this step's 4 DMA outstanding
        __builtin_amdgcn_s_barrier();
        __builtin_amdgcn_sched_barrier(0);
        if (st + 1 < NSTEP) STAGE(st + 1, (st + 1) & 1);

        const char* xb = xsec_base + (st & 1) * 16384;

        #pragma unroll
        for (int c2 = 0; c2 < 2; ++c2) {
            const int ga = c2 * 8 + 2 * (lane >> 4);
            float4 xa = *reinterpret_cast<const float4*>(xb + ((ga    ) ^ rm) * 16);
            float4 xc = *reinterpret_cast<const float4*>(xb + ((ga + 1) ^ rm) * 16);
            short8 ah, al;
            split8(xa, xc, ah, al);

            // B fragments direct from L2-resident pre-split W
            const int ksl = st * 8 + c2 * 4 + (lane >> 4);          // 0..127
            const unsigned short* bp = wBbase + ((size_t)ksl * 64 + (lane & 15)) * 8;
            short8 bh[4], bl[4];
            #pragma unroll
            for (int n = 0; n < 4; ++n) {
                bh[n] = *reinterpret_cast<const short8*>(bp + n * 128);
                bl[n] = *reinterpret_cast<const short8*>(bp + WSPLIT_SHORTS + n * 128);
            }

            #pragma unroll
            for (int n = 0; n < 4; ++n)
                acc[n] = __builtin_amdgcn_mfma_f32_16x16x32_bf16(ah, bh[n], acc[n], 0, 0, 0);
            #pragma unroll
            for (int n = 0; n < 4; ++n)
                acc[n] = __builtin_amdgcn_mfma_f32_16x16x32_bf16(ah, bl[n], acc[n], 0, 0, 0);
            #pragma unroll
            for (int n = 0; n < 4; ++n)
                acc[n] = __builtin_amdgcn_mfma_f32_16x16x32_bf16(al, bh[n], acc[n], 0, 0, 0);
        }
    }

    __syncthreads();   // full drain before LDS reuse

    // ---- 4-way k-reduce via LDS ----
    float* const part = reinterpret_cast<float*>(smem);            // 3072 f32
    float* const Lb   = reinterpret_cast<float*>(smem + 12288);    // [64 e][17]
    float* const red  = reinterpret_cast<float*>(smem + 17792);    // 512 f32

    if (ksw > 0) {
        #pragma unroll
        for (int n = 0; n < 4; ++n)
            #pragma unroll
            for (int j = 0; j < 4; ++j)
                part[(ksw - 1) * 1024 + lane * 16 + n * 4 + j] = acc[n][j];
    }
    __syncthreads();
    if (ksw == 0) {
        #pragma unroll
        for (int n = 0; n < 4; ++n) {
            #pragma unroll
            for (int j = 0; j < 4; ++j) {
                float v = acc[n][j]
                        + part[0 * 1024 + lane * 16 + n * 4 + j]
                        + part[1 * 1024 + lane * 16 + n * 4 + j]
                        + part[2 * 1024 + lane * 16 + n * 4 + j];
                // C layout (m89-verified): col = lane&15, row = (lane>>4)*4 + j
                const int e  = n * 16 + (lane & 15);
                const int rl = (lane >> 4) * 4 + j;
                Lb[e * 17 + rl] = v;
            }
        }
    }
    __syncthreads();

    // ---- softmax + top-2 per row (lane = expert), 4 rows/wave ----
    float impAcc = 0.f, cntAcc = 0.f;
    const float blane = b[lane];
    float* outIdx = out;
    float* outVal = out + (size_t)SROWS * 2;

    #pragma unroll 1
    for (int rr = 0; rr < 4; ++rr) {
        const int r = ksw * 4 + rr;
        const float logit = Lb[lane * 17 + r] + blane;

        float v1 = logit; int i1 = lane;
        #pragma unroll
        for (int off = 32; off; off >>= 1) {
            float ov = __shfl_xor(v1, off);
            int   oi = __shfl_xor(i1, off);
            if (ov > v1 || (ov == v1 && oi < i1)) { v1 = ov; i1 = oi; }
        }
        float p = expf(logit - v1);
        float ssum = p;
        #pragma unroll
        for (int off = 32; off; off >>= 1) ssum += __shfl_xor(ssum, off);

        float v2 = (lane == i1) ? -3.402823466e38f : logit;
        int i2 = lane;
        #pragma unroll
        for (int off = 32; off; off >>= 1) {
            float ov = __shfl_xor(v2, off);
            int   oi = __shfl_xor(i2, off);
            if (ov > v2 || (ov == v2 && oi < i2)) { v2 = ov; i2 = oi; }
        }

        impAcc += p / ssum;
        cntAcc += (i1 == lane) ? 1.f : 0.f;

        if (lane == 0) {
            const int sr = row0 + r;
            outIdx[sr * 2 + 0] = (float)i1;
            outIdx[sr * 2 + 1] = (float)i2;
            outVal[sr * 2 + 0] = 1.f / ssum;
            outVal[sr * 2 + 1] = expf(v2 - v1) / ssum;
        }
    }

    // ---- per-block reduce of importance / count partials ----
    __syncthreads();
    red[ksw * 64 + lane]       = impAcc;
    red[256 + ksw * 64 + lane] = cntAcc;
    __syncthreads();
    if (tid < 64) {
        float si = 0.f, sc2 = 0.f;
        #pragma unroll
        for (int g = 0; g < 4; ++g) {
            si  += red[g * 64 + tid];
            sc2 += red[256 + g * 64 + tid];
        }
        ws[WSOFF_F + (size_t)blockIdx.x * 64 + tid] = si;
        ws[WSOFF2  + (size_t)blockIdx.x * 64 + tid] = sc2;
    }
}

__global__ void gate_reduce(const float* __restrict__ ws, float* __restrict__ out)
{
    __shared__ float li[16 * 64], lc[16 * 64], lp[64];
    const int t = threadIdx.x;                 // 1024 threads
    const int e = t & 63, g = t >> 6;          // 16 groups x 64 blocks each
    float si = 0.f, sc = 0.f;
    const int base = g * 64;
    #pragma unroll 4
    for (int bb = base; bb < base + 64; ++bb) {
        si += ws[WSOFF_F + (size_t)bb * 64 + e];
        sc += ws[WSOFF2  + (size_t)bb * 64 + e];
    }
    li[g * 64 + e] = si;
    lc[g * 64 + e] = sc;
    __syncthreads();
    if (t < 64) {
        float ti = 0.f, tc = 0.f;
        #pragma unroll
        for (int gg = 0; gg < 16; ++gg) { ti += li[gg * 64 + t]; tc += lc[gg * 64 + t]; }
        lp[t] = ti * tc;
    }
    __syncthreads();
    if (t == 0) {
        float s = 0.f;
        for (int i = 0; i < NE; ++i) s += lp[i];
        out[(size_t)SROWS * 4] = s * ((float)NE / ((float)SROWS * (float)SROWS));
    }
}

extern "C" void kernel_launch(void* const* d_in, const int* in_sizes, int n_in,
                              void* d_out, int out_size, void* d_ws, size_t ws_size,
                              hipStream_t stream)
{
    const float* x = (const float*)d_in[0];
    const float* W = (const float*)d_in[1];
    const float* b = (const float*)d_in[2];
    float* out = (float*)d_out;
    unsigned short* wsp = (unsigned short*)d_ws;
    float* wsf = (float*)d_ws;

    w_split<<<128, 256, 0, stream>>>(W, wsp);
    gate_main<<<NBLK, 256, 0, stream>>>(x, wsp, b, out, wsf);
    gate_reduce<<<1, 1024, 0, stream>>>(wsf, out);
}